// Round 4
// baseline (986.866 us; speedup 1.0000x reference)
//
#include <hip/hip_runtime.h>

#define DI __device__ __forceinline__

static constexpr int NN = 20000;   // nodes
static constexpr int NE = 160000;  // edges

typedef __attribute__((ext_vector_type(8))) short bf16x8;
typedef __attribute__((ext_vector_type(4))) float f32x4;

DI float rl(float v, int lane) {
    return __int_as_float(__builtin_amdgcn_readlane(__float_as_int(v), lane));
}
DI float xr(float v, int m) { return __shfl_xor(v, m, 64); }
DI float wsum64(float v) {
    v += xr(v, 1); v += xr(v, 2); v += xr(v, 4);
    v += xr(v, 8); v += xr(v, 16); v += xr(v, 32);
    return v;
}
DI float hsum16(float v) {
    v += xr(v, 1); v += xr(v, 2); v += xr(v, 4); v += xr(v, 8);
    return v;
}
// DPP 16-lane (row) butterfly reduction: pure VALU.
DI float hsum16d(float v) {
    v += __int_as_float(__builtin_amdgcn_mov_dpp(__float_as_int(v), 0xB1, 0xF, 0xF, true));   // xor1
    v += __int_as_float(__builtin_amdgcn_mov_dpp(__float_as_int(v), 0x4E, 0xF, 0xF, true));   // xor2
    v += __int_as_float(__builtin_amdgcn_mov_dpp(__float_as_int(v), 0x141, 0xF, 0xF, true));  // half mirror
    v += __int_as_float(__builtin_amdgcn_mov_dpp(__float_as_int(v), 0x140, 0xF, 0xF, true));  // row mirror
    return v;
}
DI float wsum64v(float v) {
    v = hsum16d(v);
    return (rl(v, 0) + rl(v, 16)) + (rl(v, 32) + rl(v, 48));
}
DI float dot4(f32x4 a, f32x4 b) { return a.x * b.x + a.y * b.y + a.z * b.z + a.w * b.w; }
DI unsigned short f2bf(float x) {
    unsigned u = __float_as_uint(x) + 0x8000u;
    return (unsigned short)(u >> 16);
}
DI unsigned pack_bf2(float x, float y) {
    unsigned ux = __float_as_uint(x) + 0x8000u;
    unsigned uy = __float_as_uint(y) + 0x8000u;
#if __has_builtin(__builtin_amdgcn_perm)
    return __builtin_amdgcn_perm(uy, ux, 0x07060302u);
#else
    return (ux >> 16) | (uy & 0xFFFF0000u);
#endif
}

// ---------------- prep: W -> bf16, layout [i][o][d] (for msg MFMA) ----------------
__global__ void prep_w(const float* __restrict__ mw, unsigned short* __restrict__ Wstg) {
    int idx = blockIdx.x * 256 + threadIdx.x;   // 262144 total
    int d = idx & 63, o = (idx >> 6) & 63, i = idx >> 12;
    Wstg[idx] = f2bf(mw[(o * 64 + i) * 64 + d]);
}

// per-slot edge-independent constants:
// P[0..255] q0[m][l] | P[256..511] vc[m][l] | P[512..575] vs[l]
// P[576..591] s0[m][h]*0.25 | P[592..607] s2[m][h]*0.25
__global__ void precomp_kernel(const float* __restrict__ cls_w, const float* __restrict__ sep,
                               const float* __restrict__ in_w, const float* __restrict__ in_b,
                               float* __restrict__ P) {
    int l = threadIdx.x;  // 64 threads
    float bq = in_b[l], bk = in_b[64 + l], bv = in_b[128 + l];
    float xs = sep[l];
    float ks = bk, vs = bv;
    for (int j = 0; j < 64; j++) {
        float xj = rl(xs, j);
        ks += in_w[(64 + l) * 64 + j] * xj;
        vs += in_w[(128 + l) * 64 + j] * xj;
    }
    P[512 + l] = vs;
    for (int m = 0; m < 4; m++) {
        float xc = cls_w[m * 64 + l];
        float q0 = bq, kc = bk, vc = bv;
        for (int j = 0; j < 64; j++) {
            float xj = rl(xc, j);
            q0 += in_w[l * 64 + j] * xj;
            kc += in_w[(64 + l) * 64 + j] * xj;
            vc += in_w[(128 + l) * 64 + j] * xj;
        }
        P[m * 64 + l] = q0;
        P[256 + m * 64 + l] = vc;
        float p0 = hsum16(q0 * kc);
        float p2 = hsum16(q0 * ks);
        if ((l & 15) == 0) {
            P[576 + m * 4 + (l >> 4)] = p0 * 0.25f;
            P[592 + m * 4 + (l >> 4)] = p2 * 0.25f;
        }
    }
}

// fused small matrices derived from P + weights (single block, 256 thr)
__global__ void prep2_kernel(const float* __restrict__ in_w, const float* __restrict__ in_b,
                             const float* __restrict__ out_w,
                             const float* __restrict__ mc_w, const float* __restrict__ mc_b,
                             const float* __restrict__ ln2_g, const float* __restrict__ ln2_b,
                             const float* __restrict__ P,
                             float* __restrict__ SWg, float* __restrict__ SB16,
                             float* __restrict__ OvcG, float* __restrict__ OvsG,
                             float* __restrict__ bOvG, float* __restrict__ s0x,
                             float* __restrict__ s2x, float* __restrict__ MC8) {
    int t = threadIdx.x;
    for (int u = t; u < 1024; u += 256) {       // SW
        int m = u >> 8, h = (u >> 6) & 3, j = u & 63;
        float acc = 0.f;
        for (int i = 0; i < 16; i++)
            acc += P[m * 64 + h * 16 + i] * in_w[(64 + h * 16 + i) * 64 + j];
        SWg[u] = 0.25f * acc;
    }
    for (int u = t; u < 1024; u += 256) {       // Ovc: OvcG[(m*64+l)*4+h]
        int h = u & 3, l = (u >> 2) & 63, m = u >> 8;
        float acc = 0.f;
        for (int i = 0; i < 16; i++)
            acc += out_w[l * 64 + h * 16 + i] * P[256 + m * 64 + h * 16 + i];
        OvcG[u] = acc;
    }
    if (t < 256) {                              // Ovs, bOv
        int h = t & 3, l = t >> 2;
        float a1 = 0.f, a2 = 0.f;
        for (int i = 0; i < 16; i++) {
            a1 += out_w[l * 64 + h * 16 + i] * P[512 + h * 16 + i];
            a2 += out_w[l * 64 + h * 16 + i] * in_b[128 + h * 16 + i];
        }
        OvsG[t] = a1;
        bOvG[t] = a2;
    }
    if (t < 16) {                               // SB16, s0x, s2x
        int m = t >> 2, h = t & 3;
        float acc = 0.f;
        for (int i = 0; i < 16; i++)
            acc += P[m * 64 + h * 16 + i] * in_b[64 + h * 16 + i];
        SB16[t] = 0.25f * acc;
        int h2 = t >> 2, m2 = t & 3;
        s0x[t] = P[576 + m2 * 4 + h2];           // [h*4+m]
        s2x[t] = P[592 + m2 * 4 + h2];
    }
    if (t < 8) {                                // Mc / Cc
        int c = t & 3;
        float acc = 0.f;
        if (t < 4) {
            for (int l = 0; l < 64; l++) acc += mc_w[c * 64 + l] * ln2_g[l];
        } else {
            for (int l = 0; l < 64; l++) acc += mc_w[c * 64 + l] * ln2_b[l];
            acc += mc_b[c];
        }
        MC8[t] = acc;
    }
}

// WOVg[(j*64+l)*4+h] = sum_i out_w[l][h16+i]*Wv[h16+i][j]
__global__ void prep_wov(const float* __restrict__ in_w, const float* __restrict__ out_w,
                         float* __restrict__ WOVg) {
    int u = blockIdx.x * 256 + threadIdx.x;     // 16384
    int h = u & 3, l = (u >> 2) & 63, j = u >> 8;
    float acc = 0.f;
    for (int i = 0; i < 16; i++)
        acc += out_w[l * 64 + h * 16 + i] * in_w[(128 + h * 16 + i) * 64 + j];
    WOVg[u] = acc;
}

// ---------------- per-node stage: Eg[n][h*4+m] = exp(S), Ov[n][h][l] ----------------
__global__ __launch_bounds__(256) void node_pre(
    const float* __restrict__ feat, const float* __restrict__ SWg,
    const float* __restrict__ SB16, const float* __restrict__ WOVg,
    const float* __restrict__ bOvG, float* __restrict__ Eout, float* __restrict__ Ovout) {
    __shared__ float SWs[1024];
    __shared__ f32x4 WOVs[4096];
    int tid = threadIdx.x;
    for (int p = tid; p < 1024; p += 256) SWs[p] = SWg[p];
    for (int p = tid; p < 4096; p += 256) WOVs[p] = ((const f32x4*)WOVg)[p];
    __syncthreads();
    int w = tid >> 6, l = tid & 63;
    int n = blockIdx.x * 4 + w;
    float f = feat[(size_t)n * 64 + l];
#pragma unroll
    for (int mh = 0; mh < 16; mh++) {           // mh = m*4+h
        float v = SWs[mh * 64 + l] * f;
        v = wsum64v(v);
        if (l == mh) Eout[(size_t)n * 16 + (mh & 3) * 4 + (mh >> 2)] = __expf(v + SB16[mh]);
    }
    f32x4 acc = ((const f32x4*)bOvG)[l];
#pragma unroll 8
    for (int j = 0; j < 64; j++) {
        float fj = rl(f, j);
        f32x4 wv = WOVs[j * 64 + l];
        acc += wv * fj;
    }
#pragma unroll
    for (int h = 0; h < 4; h++)
        Ovout[((size_t)n * 4 + h) * 64 + l] = acc[h];
}

// ---------------- edge-order bookkeeping ----------------

__global__ void hist_kernel(const int* __restrict__ et, int* __restrict__ bc, int nE) {
    __shared__ int c[5];
    int t = threadIdx.x, b = blockIdx.x;
    if (t < 5) c[t] = 0;
    __syncthreads();
    int e = b * 256 + t;
    if (e < nE) atomicAdd(&c[et[e]], 1);
    __syncthreads();
    if (t < 5) bc[b * 5 + t] = c[t];
}

__global__ void scan_kernel(const int* __restrict__ bc, int* __restrict__ boff,
                            int* __restrict__ cs, int nb) {
    int t = threadIdx.x;
    if (t < 5) {
        int tot = 0;
        for (int b = 0; b < nb; b++) { boff[b * 5 + t] = tot; tot += bc[b * 5 + t]; }
        cs[t] = tot;
    }
    __syncthreads();
    if (t == 0) {
        int s = 0;
        for (int e = 0; e < 5; e++) { cs[5 + e] = s; s += cs[e]; }
    }
}

__global__ void rank_kernel(const int* __restrict__ et, const int* __restrict__ boff,
                            const int* __restrict__ cs, int* __restrict__ rowbase,
                            int* __restrict__ estride, int nE) {
    __shared__ int wc[4][5];
    int tid = threadIdx.x, b = blockIdx.x;
    int w = tid >> 6, lane = tid & 63;
    int e = b * 256 + tid;
    bool valid = e < nE;
    int my = valid ? et[e] : 0;
    unsigned long long bal[5];
#pragma unroll
    for (int ty = 0; ty < 5; ty++) bal[ty] = __ballot(valid && my == ty);
    if (lane == 0) {
#pragma unroll
        for (int ty = 0; ty < 5; ty++) wc[w][ty] = __popcll(bal[ty]);
    }
    __syncthreads();
    if (valid) {
        unsigned long long lt = ((unsigned long long)1 << lane) - 1;
        int intra = __popcll(bal[my] & lt);
        int pre = 0;
        for (int w2 = 0; w2 < w; w2++) pre += wc[w2][my];
        rowbase[e] = 4 * cs[5 + my] + boff[b * 5 + my] + pre + intra;
        estride[e] = cs[my];
    }
}

__global__ void deg_kernel(const int* __restrict__ dst, float* __restrict__ deg, int nE) {
    int e = blockIdx.x * 256 + threadIdx.x;
    if (e < nE) atomicAdd(&deg[dst[e]], 1.0f);
}

// ---------------- encoder v3: 4 items/wave, 16 lanes/item, 4 dims/lane ----------------
// Requires count % 32 == 0 (NE=160000, NN=20000 both divide 32).

template <bool NODE>
__global__ __launch_bounds__(512, 4) void enc3_kernel(
    const int* __restrict__ src, const int* __restrict__ dst,
    const float* __restrict__ Eg, const float* __restrict__ Ovg,
    const float* __restrict__ OvcG, const float* __restrict__ OvsG,
    const float* __restrict__ E0x, const float* __restrict__ E2x,
    const float* __restrict__ MC8,
    const float* __restrict__ cls_w, const float* __restrict__ out_b,
    const float* __restrict__ ln1_g, const float* __restrict__ ln1_b,
    const float* __restrict__ ln2_g, const float* __restrict__ ln2_b,
    const float* __restrict__ ff1_w, const float* __restrict__ ff1_b,
    const float* __restrict__ ff2_w, const float* __restrict__ ff2_b,
    const float* __restrict__ mc_w,
    const int* __restrict__ rowbase, const int* __restrict__ estride,
    float* __restrict__ mem_out, float* __restrict__ out_cat, float* __restrict__ out_label,
    int count) {
    // row stride 68 floats = 272B (16B-aligned, bank-offset 4)
    __shared__ float OcS[16 * 68];   // [(m*4+h)][l]
    __shared__ float OsS[4 * 68];    // [h][l]
    __shared__ float clsS[4 * 68];   // [m][l] = cls + out_b
    __shared__ float F1T[16 * 68];   // [f][j]
    __shared__ float F2T[16 * 68];   // [f][l]
    __shared__ float mcgS[4 * 68];   // [c][l] = mc_w[c][l]*g2[l]
    __shared__ float scr[8 * 272];   // per-wave scratch: 68 x f32x4 units (wS->xS->hS->pS)

    int tid = threadIdx.x;
    for (int p = tid; p < 1024; p += 512) {
        int m = p >> 8, h = (p >> 6) & 3, l = p & 63;
        OcS[(m * 4 + h) * 68 + l] = OvcG[(m * 64 + l) * 4 + h];
        int f = p >> 6, j = p & 63;
        F1T[f * 68 + j] = ff1_w[p];                  // ff1_w[f*64+j]
        F2T[f * 68 + j] = ff2_w[j * 16 + f];         // [f][l]
    }
    if (tid < 256) {
        int h = tid & 3, l = tid >> 2;
        OsS[h * 68 + l] = OvsG[l * 4 + h];
        int m = tid >> 6, l2 = tid & 63;
        clsS[m * 68 + l2] = cls_w[m * 64 + l2] + out_b[l2];
        int c = tid >> 6;
        mcgS[c * 68 + l2] = mc_w[c * 64 + l2] * ln2_g[l2];
    }
    __syncthreads();

    int w = tid >> 6, lane = tid & 63;
    int g = lane >> 4, t = lane & 15;
    float* myscr = scr + w * 272;                    // 68 f32x4 units
    int item = blockIdx.x * 32 + w * 4 + g;

    int ia = NODE ? item : src[item];
    int ib = NODE ? item : dst[item];
    float Ea = Eg[(size_t)ia * 16 + t];
    float Eb = NODE ? Ea : Eg[(size_t)ib * 16 + t];
    f32x4 OvA[4], OvB[4];
#pragma unroll
    for (int h = 0; h < 4; h++) {
        OvA[h] = *(const f32x4*)(Ovg + ((size_t)ia * 4 + h) * 64 + 4 * t);
        OvB[h] = NODE ? OvA[h] : *(const f32x4*)(Ovg + ((size_t)ib * 4 + h) * 64 + 4 * t);
    }
    float E0c = __expf(E0x[t]), E2c = __expf(E2x[t]);
    f32x4 g1v = *(const f32x4*)(ln1_g + 4 * t);
    f32x4 b1v = *(const f32x4*)(ln1_b + 4 * t);
    f32x4 g2v = *(const f32x4*)(ln2_g + 4 * t);
    f32x4 b2v = *(const f32x4*)(ln2_b + 4 * t);
    f32x4 f2bv = *(const f32x4*)(ff2_b + 4 * t);
    float f1b = ff1_b[t];
    int rb = 0, st = 0;
    if (!NODE) { rb = rowbase[item]; st = estride[item]; }

    // softmax (no max-shift; scores |s| <~ 1.5): lane t owns combo (h=t>>2, m=t&3)
    {
        float den = E0c + Ea + E2c + Eb;
        float inv = 1.f / den;
        f32x4 wv = {E0c * inv, Ea * inv, E2c * inv, Eb * inv};
        *(f32x4*)&myscr[(g * 17 + t) * 4] = wv;      // wS
    }

    // Stage A: attention combine + LN1 per slot
    f32x4 x1a[4];
#pragma unroll
    for (int m = 0; m < 4; m++) {
        f32x4 x = *(const f32x4*)&clsS[m * 68 + 4 * t];
#pragma unroll
        for (int h = 0; h < 4; h++) {
            f32x4 wq = *(const f32x4*)&myscr[(g * 17 + h * 4 + m) * 4];
            f32x4 oc = *(const f32x4*)&OcS[(m * 4 + h) * 68 + 4 * t];
            f32x4 os = *(const f32x4*)&OsS[h * 68 + 4 * t];
            x += oc * wq.x + OvA[h] * wq.y + os * wq.z + OvB[h] * wq.w;
        }
        float s = (x.x + x.y) + (x.z + x.w);
        float s2 = dot4(x, x);
        s = hsum16d(s); s2 = hsum16d(s2);
        float mu = s * (1.f / 64.f);
        float var = s2 * (1.f / 64.f) - mu * mu;
        float r1 = rsqrtf(var + 1e-5f);
        x1a[m] = (x - mu) * (r1 * g1v) + b1v;
    }

    // Stage B1: FF1, hidden unit = lane t (no redundancy); scr reused as xS per slot
    float hr[4];
#pragma unroll
    for (int m = 0; m < 4; m++) {
        *(f32x4*)&myscr[(g * 17 + t) * 4] = x1a[m];
        float hp = 0.f;
#pragma unroll
        for (int tj = 0; tj < 16; tj++) {
            f32x4 f1 = *(const f32x4*)&F1T[t * 68 + 4 * tj];
            f32x4 xv = *(const f32x4*)&myscr[(g * 17 + tj) * 4];
            hp += dot4(f1, xv);
        }
        hr[m] = fmaxf(hp + f1b, 0.f);
    }

    // Stage B2: FF2; scr reused as hS
    {
        f32x4 hv = {hr[0], hr[1], hr[2], hr[3]};
        *(f32x4*)&myscr[(g * 17 + t) * 4] = hv;
    }
    f32x4 y[4];
#pragma unroll
    for (int m = 0; m < 4; m++) y[m] = x1a[m] + f2bv;
#pragma unroll
    for (int tf = 0; tf < 16; tf++) {
        f32x4 hh = *(const f32x4*)&myscr[(g * 17 + tf) * 4];
        f32x4 f2 = *(const f32x4*)&F2T[tf * 68 + 4 * t];
        y[0] += f2 * hh.x;
        y[1] += f2 * hh.y;
        y[2] += f2 * hh.z;
        y[3] += f2 * hh.w;
    }

    // Stage C: LN2 + mem (+ cat for edges); scr reused as pS per slot
    f32x4 Mc, Cc;
    if (!NODE) { Mc = ((const f32x4*)MC8)[0]; Cc = ((const f32x4*)MC8)[1]; }
    f32x4 mem = {0.f, 0.f, 0.f, 0.f};
#pragma unroll
    for (int m = 0; m < 4; m++) {
        f32x4 ym = y[m];
        float s = (ym.x + ym.y) + (ym.z + ym.w);
        float s2 = dot4(ym, ym);
        s = hsum16d(s); s2 = hsum16d(s2);
        float mu2 = s * (1.f / 64.f);
        float var2 = s2 * (1.f / 64.f) - mu2 * mu2;
        float r2 = rsqrtf(var2 + 1e-5f);
        mem += (ym - mu2) * (r2 * g2v) + b2v;
        if (!NODE) {
            f32x4 p;
#pragma unroll
            for (int c = 0; c < 4; c++) {
                f32x4 mc = *(const f32x4*)&mcgS[c * 68 + 4 * t];
                p[c] = dot4(mc, ym);
            }
            *(f32x4*)&myscr[(g * 17 + t) * 4] = p;
            int cs = t & 3;
            float d = 0.f;
#pragma unroll
            for (int tj = 0; tj < 16; tj++) d += myscr[(g * 17 + tj) * 4 + cs];
            float Mcc = cs == 0 ? Mc.x : (cs == 1 ? Mc.y : (cs == 2 ? Mc.z : Mc.w));
            float Ccc = cs == 0 ? Cc.x : (cs == 1 ? Cc.y : (cs == 2 ? Cc.z : Cc.w));
            float cval = r2 * (d - mu2 * Mcc) + Ccc;
            int row = rb + m * st;
            if (t < 4) out_cat[(size_t)row * 4 + t] = cval;
            if (t == 0) out_label[row] = (float)m;
        }
    }
    *(f32x4*)(mem_out + (size_t)item * 64 + 4 * t) = mem;
}

// ---------------- message bilinear via MFMA (unchanged) ----------------

template <bool NODE>
__global__ __launch_bounds__(256, 2) void msg_mfma(
    const float* __restrict__ feat, const int* __restrict__ src, const int* __restrict__ dstv,
    const float* __restrict__ memv, const unsigned short* __restrict__ Wstg,
    float* __restrict__ outv, int count) {
    constexpr int RS = 72;
    __shared__ __align__(16) unsigned short Wt[4 * 64 * RS];
    __shared__ float hT[4 * 256];
    int tid = threadIdx.x;
    int w = tid >> 6, lane = tid & 63;
    int m16 = lane & 15, q = lane >> 4;
    int blockbase = blockIdx.x * 256;
    int wavebase = w * 64;

    float memf[4][2][8];
#pragma unroll
    for (int Mt = 0; Mt < 4; Mt++) {
        int it = blockbase + wavebase + Mt * 16 + m16;
        if (it >= count) it = count - 1;
        const float* mrow = memv + (size_t)it * 64;
#pragma unroll
        for (int ks = 0; ks < 2; ks++) {
            float4 a = *(const float4*)(mrow + ks * 32 + q * 8);
            float4 b = *(const float4*)(mrow + ks * 32 + q * 8 + 4);
            memf[Mt][ks][0] = a.x; memf[Mt][ks][1] = a.y;
            memf[Mt][ks][2] = a.z; memf[Mt][ks][3] = a.w;
            memf[Mt][ks][4] = b.x; memf[Mt][ks][5] = b.y;
            memf[Mt][ks][6] = b.z; memf[Mt][ks][7] = b.w;
        }
    }
    f32x4 acc[4][4];
#pragma unroll
    for (int Mt = 0; Mt < 4; Mt++)
#pragma unroll
        for (int nt = 0; nt < 4; nt++) {
            f32x4 z = {0.f, 0.f, 0.f, 0.f};
            acc[Mt][nt] = z;
        }

    for (int ch = 0; ch < 16; ch++) {
        __syncthreads();
        const unsigned short* gsl = Wstg + (size_t)ch * 4 * 4096;
#pragma unroll
        for (int p = 0; p < 8; p++) {
            int flat = p * 2048 + tid * 8;
            int ic = flat >> 12, o = (flat >> 6) & 63, d = flat & 63;
            uint4 v = *(const uint4*)(gsl + flat);
            *(uint4*)&Wt[(ic * 64 + o) * RS + d] = v;
        }
        {
            int it = blockbase + tid;
            if (it >= count) it = count - 1;
            int hidx = NODE ? it : src[it];
            float4 hv = *(const float4*)(feat + (size_t)hidx * 64 + ch * 4);
            hT[0 * 256 + tid] = hv.x;
            hT[1 * 256 + tid] = hv.y;
            hT[2 * 256 + tid] = hv.z;
            hT[3 * 256 + tid] = hv.w;
        }
        __syncthreads();

#pragma unroll
        for (int il = 0; il < 4; il++) {
            float hM[4];
#pragma unroll
            for (int Mt = 0; Mt < 4; Mt++)
                hM[Mt] = hT[il * 256 + wavebase + Mt * 16 + m16];
            bf16x8 afr[4][2];
#pragma unroll
            for (int Mt = 0; Mt < 4; Mt++)
#pragma unroll
                for (int ks = 0; ks < 2; ks++) {
                    union { unsigned u[4]; bf16x8 v; } uu;
#pragma unroll
                    for (int jj = 0; jj < 4; jj++) {
                        float p0 = memf[Mt][ks][jj * 2 + 0] * hM[Mt];
                        float p1 = memf[Mt][ks][jj * 2 + 1] * hM[Mt];
                        uu.u[jj] = pack_bf2(p0, p1);
                    }
                    afr[Mt][ks] = uu.v;
                }
            const unsigned short* wrow = &Wt[(il * 64) * RS];
#pragma unroll
            for (int nt = 0; nt < 4; nt++) {
#pragma unroll
                for (int ks = 0; ks < 2; ks++) {
                    int o = nt * 16 + m16;
                    union { uint4 u; bf16x8 v; } bb;
                    bb.u = *(const uint4*)&wrow[o * RS + ks * 32 + q * 8];
#pragma unroll
                    for (int Mt = 0; Mt < 4; Mt++)
                        acc[Mt][nt] = __builtin_amdgcn_mfma_f32_16x16x32_bf16(
                            afr[Mt][ks], bb.v, acc[Mt][nt], 0, 0, 0);
                }
            }
        }
    }
#pragma unroll
    for (int Mt = 0; Mt < 4; Mt++) {
        int ib = blockbase + wavebase + Mt * 16 + q * 4;
        if (NODE) {
#pragma unroll
            for (int r = 0; r < 4; r++) {
                int it = ib + r;
                if (it < count) {
#pragma unroll
                    for (int nt = 0; nt < 4; nt++)
                        outv[(size_t)it * 64 + nt * 16 + m16] = acc[Mt][nt][r];
                }
            }
        } else {
            int4 dd = *(const int4*)(dstv + ib);
#pragma unroll
            for (int r = 0; r < 4; r++) {
                int it = ib + r;
                if (it < count) {
                    int dn = (&dd.x)[r];
#pragma unroll
                    for (int nt = 0; nt < 4; nt++)
                        atomicAdd(&outv[(size_t)dn * 64 + nt * 16 + m16], acc[Mt][nt][r]);
                }
            }
        }
    }
}

// ---------------- final node combine ----------------

__global__ __launch_bounds__(256) void final_kernel(
    const float* __restrict__ agg, const float* __restrict__ deg, const float* __restrict__ msgn,
    const float* __restrict__ lnw_g, const float* __restrict__ lnw_b,
    const float* __restrict__ h_bias, float* __restrict__ outp, int nN) {
    int tid = threadIdx.x, w = tid >> 6, l = tid & 63;
    int n = blockIdx.x * 4 + w;
    if (n >= nN) return;
    float a = agg[(size_t)n * 64 + l] / fmaxf(deg[n], 1.f);
    float mu = wsum64(a) * (1.f / 64.f);
    float d = a - mu;
    float var = wsum64(d * d) * (1.f / 64.f);
    float v = d * rsqrtf(var + 1e-5f) * lnw_g[l] + lnw_b[l] + h_bias[l] + msgn[(size_t)n * 64 + l];
    outp[(size_t)n * 64 + l] = v > 0.f ? v : 0.2f * v;
}

// ---------------- host ----------------

extern "C" void kernel_launch(void* const* d_in, const int* in_sizes, int n_in,
                              void* d_out, int out_size, void* d_ws, size_t ws_size,
                              hipStream_t stream) {
    const float* feat   = (const float*)d_in[0];
    const int*   src    = (const int*)d_in[1];
    const int*   dst    = (const int*)d_in[2];
    const int*   etype  = (const int*)d_in[3];
    const float* cls_w  = (const float*)d_in[4];
    const float* sep    = (const float*)d_in[5];
    const float* in_w   = (const float*)d_in[6];
    const float* in_b   = (const float*)d_in[7];
    const float* out_w  = (const float*)d_in[8];
    const float* out_b  = (const float*)d_in[9];
    const float* ln1_g  = (const float*)d_in[10];
    const float* ln1_b  = (const float*)d_in[11];
    const float* ln2_g  = (const float*)d_in[12];
    const float* ln2_b  = (const float*)d_in[13];
    const float* ff1_w  = (const float*)d_in[14];
    const float* ff1_b  = (const float*)d_in[15];
    const float* ff2_w  = (const float*)d_in[16];
    const float* ff2_b  = (const float*)d_in[17];
    const float* mc_w   = (const float*)d_in[18];
    const float* mc_b   = (const float*)d_in[19];
    const float* memw_w = (const float*)d_in[20];
    const float* h_bias = (const float*)d_in[21];
    const float* lnw_g  = (const float*)d_in[22];
    const float* lnw_b  = (const float*)d_in[23];

    char* ws = (char*)d_ws;
    size_t off = 0;
    auto nxt = [&](size_t bytes) -> void* {
        void* p = ws + off;
        off += (bytes + 255) & ~(size_t)255;
        return p;
    };
    unsigned short* Wstg = (unsigned short*)nxt(64 * 64 * 64 * sizeof(unsigned short));
    float* P       = (float*)nxt(1024 * sizeof(float));
    float* SWg     = (float*)nxt(1024 * sizeof(float));
    float* SB16    = (float*)nxt(16 * sizeof(float));
    float* OvcG    = (float*)nxt(1024 * sizeof(float));
    float* OvsG    = (float*)nxt(256 * sizeof(float));
    float* bOvG    = (float*)nxt(256 * sizeof(float));
    float* s0x     = (float*)nxt(16 * sizeof(float));
    float* s2x     = (float*)nxt(16 * sizeof(float));
    float* MC8     = (float*)nxt(8 * sizeof(float));
    float* WOVg    = (float*)nxt(16384 * sizeof(float));
    float* Eg      = (float*)nxt((size_t)NN * 16 * sizeof(float));
    float* Ovg     = (float*)nxt((size_t)NN * 256 * sizeof(float));
    int*   bc      = (int*)nxt(625 * 5 * sizeof(int));
    int*   boff    = (int*)nxt(625 * 5 * sizeof(int));
    int*   cs      = (int*)nxt(16 * sizeof(int));
    int*   rowbase = (int*)nxt((size_t)NE * sizeof(int));
    int*   estride = (int*)nxt((size_t)NE * sizeof(int));
    float* mem_e   = (float*)nxt((size_t)NE * 64 * sizeof(float));
    float* mem_n   = (float*)nxt((size_t)NN * 64 * sizeof(float));
    float* agg     = (float*)nxt((size_t)NN * 64 * sizeof(float));
    float* deg     = (float*)nxt((size_t)NN * sizeof(float));
    float* msg_n   = (float*)nxt((size_t)NN * 64 * sizeof(float));
    (void)ws_size; (void)in_sizes; (void)n_in; (void)out_size;

    float* out_node  = (float*)d_out;
    float* out_cat   = out_node + (size_t)NN * 64;
    float* out_label = out_cat + (size_t)4 * NE * 4;

    hipMemsetAsync(agg, 0, (size_t)NN * 64 * sizeof(float), stream);
    hipMemsetAsync(deg, 0, (size_t)NN * sizeof(float), stream);

    prep_w<<<1024, 256, 0, stream>>>(memw_w, Wstg);
    precomp_kernel<<<1, 64, 0, stream>>>(cls_w, sep, in_w, in_b, P);
    prep2_kernel<<<1, 256, 0, stream>>>(in_w, in_b, out_w, mc_w, mc_b, ln2_g, ln2_b, P,
                                        SWg, SB16, OvcG, OvsG, bOvG, s0x, s2x, MC8);
    prep_wov<<<64, 256, 0, stream>>>(in_w, out_w, WOVg);

    int nb = (NE + 255) / 256;  // 625
    hist_kernel<<<nb, 256, 0, stream>>>(etype, bc, NE);
    scan_kernel<<<1, 64, 0, stream>>>(bc, boff, cs, nb);
    rank_kernel<<<nb, 256, 0, stream>>>(etype, boff, cs, rowbase, estride, NE);
    deg_kernel<<<nb, 256, 0, stream>>>(dst, deg, NE);

    node_pre<<<NN / 4, 256, 0, stream>>>(feat, SWg, SB16, WOVg, bOvG, Eg, Ovg);

    enc3_kernel<false><<<NE / 32, 512, 0, stream>>>(
        src, dst, Eg, Ovg, OvcG, OvsG, s0x, s2x, MC8, cls_w, out_b,
        ln1_g, ln1_b, ln2_g, ln2_b, ff1_w, ff1_b, ff2_w, ff2_b, mc_w,
        rowbase, estride, mem_e, out_cat, out_label, NE);
    enc3_kernel<true><<<NN / 32, 512, 0, stream>>>(
        nullptr, nullptr, Eg, Ovg, OvcG, OvsG, s0x, s2x, MC8, cls_w, out_b,
        ln1_g, ln1_b, ln2_g, ln2_b, ff1_w, ff1_b, ff2_w, ff2_b, mc_w,
        nullptr, nullptr, mem_n, nullptr, nullptr, NN);

    msg_mfma<false><<<(NE + 255) / 256, 256, 0, stream>>>(feat, src, dst, mem_e, Wstg, agg, NE);
    msg_mfma<true><<<(NN + 255) / 256, 256, 0, stream>>>(feat, nullptr, nullptr, mem_n, Wstg, msg_n, NN);

    final_kernel<<<(NN + 3) / 4, 256, 0, stream>>>(agg, deg, msg_n, lnw_g, lnw_b, h_bias, out_node, NN);
}

// Round 5
// 973.997 us; speedup vs baseline: 1.0132x; 1.0132x over previous
//
#include <hip/hip_runtime.h>

#define DI __device__ __forceinline__

static constexpr int NN = 20000;   // nodes
static constexpr int NE = 160000;  // edges

typedef __attribute__((ext_vector_type(8))) short bf16x8;
typedef __attribute__((ext_vector_type(4))) float f32x4;

DI float rl(float v, int lane) {
    return __int_as_float(__builtin_amdgcn_readlane(__float_as_int(v), lane));
}
DI float xr(float v, int m) { return __shfl_xor(v, m, 64); }
DI float wsum64(float v) {
    v += xr(v, 1); v += xr(v, 2); v += xr(v, 4);
    v += xr(v, 8); v += xr(v, 16); v += xr(v, 32);
    return v;
}
DI float hsum16(float v) {
    v += xr(v, 1); v += xr(v, 2); v += xr(v, 4); v += xr(v, 8);
    return v;
}
// DPP 16-lane (row) butterfly reduction: pure VALU.
DI float hsum16d(float v) {
    v += __int_as_float(__builtin_amdgcn_mov_dpp(__float_as_int(v), 0xB1, 0xF, 0xF, true));   // xor1
    v += __int_as_float(__builtin_amdgcn_mov_dpp(__float_as_int(v), 0x4E, 0xF, 0xF, true));   // xor2
    v += __int_as_float(__builtin_amdgcn_mov_dpp(__float_as_int(v), 0x141, 0xF, 0xF, true));  // half mirror
    v += __int_as_float(__builtin_amdgcn_mov_dpp(__float_as_int(v), 0x140, 0xF, 0xF, true));  // row mirror
    return v;
}
DI float wsum64v(float v) {
    v = hsum16d(v);
    return (rl(v, 0) + rl(v, 16)) + (rl(v, 32) + rl(v, 48));
}
DI float dot4(f32x4 a, f32x4 b) { return a.x * b.x + a.y * b.y + a.z * b.z + a.w * b.w; }
DI unsigned short f2bf(float x) {
    unsigned u = __float_as_uint(x) + 0x8000u;
    return (unsigned short)(u >> 16);
}
DI unsigned pack_bf2(float x, float y) {
    unsigned ux = __float_as_uint(x) + 0x8000u;
    unsigned uy = __float_as_uint(y) + 0x8000u;
#if __has_builtin(__builtin_amdgcn_perm)
    return __builtin_amdgcn_perm(uy, ux, 0x07060302u);
#else
    return (ux >> 16) | (uy & 0xFFFF0000u);
#endif
}

// ---------------- prep: W -> bf16, layout [i][o][d] (for msg MFMA) ----------------
__global__ void prep_w(const float* __restrict__ mw, unsigned short* __restrict__ Wstg) {
    int idx = blockIdx.x * 256 + threadIdx.x;   // 262144 total
    int d = idx & 63, o = (idx >> 6) & 63, i = idx >> 12;
    Wstg[idx] = f2bf(mw[(o * 64 + i) * 64 + d]);
}

// per-slot edge-independent constants:
// P[0..255] q0[m][l] | P[256..511] vc[m][l] | P[512..575] vs[l]
// P[576..591] s0[m][h]*0.25 | P[592..607] s2[m][h]*0.25
__global__ void precomp_kernel(const float* __restrict__ cls_w, const float* __restrict__ sep,
                               const float* __restrict__ in_w, const float* __restrict__ in_b,
                               float* __restrict__ P) {
    int l = threadIdx.x;  // 64 threads
    float bq = in_b[l], bk = in_b[64 + l], bv = in_b[128 + l];
    float xs = sep[l];
    float ks = bk, vs = bv;
    for (int j = 0; j < 64; j++) {
        float xj = rl(xs, j);
        ks += in_w[(64 + l) * 64 + j] * xj;
        vs += in_w[(128 + l) * 64 + j] * xj;
    }
    P[512 + l] = vs;
    for (int m = 0; m < 4; m++) {
        float xc = cls_w[m * 64 + l];
        float q0 = bq, kc = bk, vc = bv;
        for (int j = 0; j < 64; j++) {
            float xj = rl(xc, j);
            q0 += in_w[l * 64 + j] * xj;
            kc += in_w[(64 + l) * 64 + j] * xj;
            vc += in_w[(128 + l) * 64 + j] * xj;
        }
        P[m * 64 + l] = q0;
        P[256 + m * 64 + l] = vc;
        float p0 = hsum16(q0 * kc);
        float p2 = hsum16(q0 * ks);
        if ((l & 15) == 0) {
            P[576 + m * 4 + (l >> 4)] = p0 * 0.25f;
            P[592 + m * 4 + (l >> 4)] = p2 * 0.25f;
        }
    }
}

// fused small matrices derived from P + weights (single block, 256 thr)
__global__ void prep2_kernel(const float* __restrict__ in_w, const float* __restrict__ in_b,
                             const float* __restrict__ out_w,
                             const float* __restrict__ mc_w, const float* __restrict__ mc_b,
                             const float* __restrict__ ln2_g, const float* __restrict__ ln2_b,
                             const float* __restrict__ P,
                             float* __restrict__ SWg, float* __restrict__ SB16,
                             float* __restrict__ OvcG, float* __restrict__ OvsG,
                             float* __restrict__ bOvG, float* __restrict__ s0x,
                             float* __restrict__ s2x, float* __restrict__ MC8) {
    int t = threadIdx.x;
    for (int u = t; u < 1024; u += 256) {       // SW
        int m = u >> 8, h = (u >> 6) & 3, j = u & 63;
        float acc = 0.f;
        for (int i = 0; i < 16; i++)
            acc += P[m * 64 + h * 16 + i] * in_w[(64 + h * 16 + i) * 64 + j];
        SWg[u] = 0.25f * acc;
    }
    for (int u = t; u < 1024; u += 256) {       // Ovc: OvcG[(m*64+l)*4+h]
        int h = u & 3, l = (u >> 2) & 63, m = u >> 8;
        float acc = 0.f;
        for (int i = 0; i < 16; i++)
            acc += out_w[l * 64 + h * 16 + i] * P[256 + m * 64 + h * 16 + i];
        OvcG[u] = acc;
    }
    if (t < 256) {                              // Ovs, bOv
        int h = t & 3, l = t >> 2;
        float a1 = 0.f, a2 = 0.f;
        for (int i = 0; i < 16; i++) {
            a1 += out_w[l * 64 + h * 16 + i] * P[512 + h * 16 + i];
            a2 += out_w[l * 64 + h * 16 + i] * in_b[128 + h * 16 + i];
        }
        OvsG[t] = a1;
        bOvG[t] = a2;
    }
    if (t < 16) {                               // SB16, s0x, s2x
        int m = t >> 2, h = t & 3;
        float acc = 0.f;
        for (int i = 0; i < 16; i++)
            acc += P[m * 64 + h * 16 + i] * in_b[64 + h * 16 + i];
        SB16[t] = 0.25f * acc;
        int h2 = t >> 2, m2 = t & 3;
        s0x[t] = P[576 + m2 * 4 + h2];           // [h*4+m]
        s2x[t] = P[592 + m2 * 4 + h2];
    }
    if (t < 8) {                                // Mc / Cc
        int c = t & 3;
        float acc = 0.f;
        if (t < 4) {
            for (int l = 0; l < 64; l++) acc += mc_w[c * 64 + l] * ln2_g[l];
        } else {
            for (int l = 0; l < 64; l++) acc += mc_w[c * 64 + l] * ln2_b[l];
            acc += mc_b[c];
        }
        MC8[t] = acc;
    }
}

// WOVg[(j*64+l)*4+h] = sum_i out_w[l][h16+i]*Wv[h16+i][j]
__global__ void prep_wov(const float* __restrict__ in_w, const float* __restrict__ out_w,
                         float* __restrict__ WOVg) {
    int u = blockIdx.x * 256 + threadIdx.x;     // 16384
    int h = u & 3, l = (u >> 2) & 63, j = u >> 8;
    float acc = 0.f;
    for (int i = 0; i < 16; i++)
        acc += out_w[l * 64 + h * 16 + i] * in_w[(128 + h * 16 + i) * 64 + j];
    WOVg[u] = acc;
}

// ---------------- per-node stage: Eg[n][h*4+m] = exp(S), Ov[n][h][l] ----------------
__global__ __launch_bounds__(256) void node_pre(
    const float* __restrict__ feat, const float* __restrict__ SWg,
    const float* __restrict__ SB16, const float* __restrict__ WOVg,
    const float* __restrict__ bOvG, float* __restrict__ Eout, float* __restrict__ Ovout) {
    __shared__ float SWs[1024];
    __shared__ f32x4 WOVs[4096];
    int tid = threadIdx.x;
    for (int p = tid; p < 1024; p += 256) SWs[p] = SWg[p];
    for (int p = tid; p < 4096; p += 256) WOVs[p] = ((const f32x4*)WOVg)[p];
    __syncthreads();
    int w = tid >> 6, l = tid & 63;
    int n = blockIdx.x * 4 + w;
    float f = feat[(size_t)n * 64 + l];
#pragma unroll
    for (int mh = 0; mh < 16; mh++) {           // mh = m*4+h
        float v = SWs[mh * 64 + l] * f;
        v = wsum64v(v);
        if (l == mh) Eout[(size_t)n * 16 + (mh & 3) * 4 + (mh >> 2)] = __expf(v + SB16[mh]);
    }
    f32x4 acc = ((const f32x4*)bOvG)[l];
#pragma unroll 8
    for (int j = 0; j < 64; j++) {
        float fj = rl(f, j);
        f32x4 wv = WOVs[j * 64 + l];
        acc += wv * fj;
    }
#pragma unroll
    for (int h = 0; h < 4; h++)
        Ovout[((size_t)n * 4 + h) * 64 + l] = acc[h];
}

// ---------------- edge-order bookkeeping ----------------

__global__ void hist_kernel(const int* __restrict__ et, int* __restrict__ bc, int nE) {
    __shared__ int c[5];
    int t = threadIdx.x, b = blockIdx.x;
    if (t < 5) c[t] = 0;
    __syncthreads();
    int e = b * 256 + t;
    if (e < nE) atomicAdd(&c[et[e]], 1);
    __syncthreads();
    if (t < 5) bc[b * 5 + t] = c[t];
}

__global__ void scan_kernel(const int* __restrict__ bc, int* __restrict__ boff,
                            int* __restrict__ cs, int nb) {
    int t = threadIdx.x;
    if (t < 5) {
        int tot = 0;
        for (int b = 0; b < nb; b++) { boff[b * 5 + t] = tot; tot += bc[b * 5 + t]; }
        cs[t] = tot;
    }
    __syncthreads();
    if (t == 0) {
        int s = 0;
        for (int e = 0; e < 5; e++) { cs[5 + e] = s; s += cs[e]; }
    }
}

__global__ void rank_kernel(const int* __restrict__ et, const int* __restrict__ boff,
                            const int* __restrict__ cs, int* __restrict__ rowbase,
                            int* __restrict__ estride, int nE) {
    __shared__ int wc[4][5];
    int tid = threadIdx.x, b = blockIdx.x;
    int w = tid >> 6, lane = tid & 63;
    int e = b * 256 + tid;
    bool valid = e < nE;
    int my = valid ? et[e] : 0;
    unsigned long long bal[5];
#pragma unroll
    for (int ty = 0; ty < 5; ty++) bal[ty] = __ballot(valid && my == ty);
    if (lane == 0) {
#pragma unroll
        for (int ty = 0; ty < 5; ty++) wc[w][ty] = __popcll(bal[ty]);
    }
    __syncthreads();
    if (valid) {
        unsigned long long lt = ((unsigned long long)1 << lane) - 1;
        int intra = __popcll(bal[my] & lt);
        int pre = 0;
        for (int w2 = 0; w2 < w; w2++) pre += wc[w2][my];
        rowbase[e] = 4 * cs[5 + my] + boff[b * 5 + my] + pre + intra;
        estride[e] = cs[my];
    }
}

__global__ void deg_kernel(const int* __restrict__ dst, float* __restrict__ deg, int nE) {
    int e = blockIdx.x * 256 + threadIdx.x;
    if (e < nE) atomicAdd(&deg[dst[e]], 1.0f);
}

// ---------------- encoder v4: 4 items/wave, 16 lanes/item, 4 dims/lane ----------------
// 256-thread blocks, __launch_bounds__(256,4) -> 128 VGPRs (R4's 64-reg cap spilled ~1GB
// of scratch; this is the fix). Requires count % 16 == 0.

template <bool NODE>
__global__ __launch_bounds__(256, 4) void enc4_kernel(
    const int* __restrict__ src, const int* __restrict__ dst,
    const float* __restrict__ Eg, const float* __restrict__ Ovg,
    const float* __restrict__ OvcG, const float* __restrict__ OvsG,
    const float* __restrict__ E0x, const float* __restrict__ E2x,
    const float* __restrict__ MC8,
    const float* __restrict__ cls_w, const float* __restrict__ out_b,
    const float* __restrict__ ln1_g, const float* __restrict__ ln1_b,
    const float* __restrict__ ln2_g, const float* __restrict__ ln2_b,
    const float* __restrict__ ff1_w, const float* __restrict__ ff1_b,
    const float* __restrict__ ff2_w, const float* __restrict__ ff2_b,
    const float* __restrict__ mc_w,
    const int* __restrict__ rowbase, const int* __restrict__ estride,
    float* __restrict__ mem_out, float* __restrict__ out_cat, float* __restrict__ out_label,
    int count) {
    // row stride 68 floats = 272B (16B-aligned, bank-offset 4)
    __shared__ float OcS[16 * 68];   // [(m*4+h)][l]
    __shared__ float OsS[4 * 68];    // [h][l]
    __shared__ float clsS[4 * 68];   // [m][l] = cls + out_b
    __shared__ float F1T[16 * 68];   // [f][j]
    __shared__ float F2T[16 * 68];   // [f][l]
    __shared__ float mcgS[4 * 68];   // [c][l] = mc_w[c][l]*g2[l]
    __shared__ float scr[4 * 272];   // per-wave scratch: 68 x f32x4 units (wS->xS->hS->pS)

    int tid = threadIdx.x;
    for (int p = tid; p < 1024; p += 256) {
        int m = p >> 8, h = (p >> 6) & 3, l = p & 63;
        OcS[(m * 4 + h) * 68 + l] = OvcG[(m * 64 + l) * 4 + h];
        int f = p >> 6, j = p & 63;
        F1T[f * 68 + j] = ff1_w[p];                  // ff1_w[f*64+j]
        F2T[f * 68 + j] = ff2_w[j * 16 + f];         // [f][l]
    }
    {
        int h = tid & 3, l = tid >> 2;
        OsS[h * 68 + l] = OvsG[l * 4 + h];
        int m = tid >> 6, l2 = tid & 63;
        clsS[m * 68 + l2] = cls_w[m * 64 + l2] + out_b[l2];
        int c = tid >> 6;
        mcgS[c * 68 + l2] = mc_w[c * 64 + l2] * ln2_g[l2];
    }
    __syncthreads();

    int w = tid >> 6, lane = tid & 63;
    int g = lane >> 4, t = lane & 15;
    float* myscr = scr + w * 272;                    // 68 f32x4 units
    int item = blockIdx.x * 16 + w * 4 + g;

    int ia = NODE ? item : src[item];
    int ib = NODE ? item : dst[item];
    float Ea = Eg[(size_t)ia * 16 + t];
    float Eb = NODE ? Ea : Eg[(size_t)ib * 16 + t];
    f32x4 OvA[4], OvB[4];
#pragma unroll
    for (int h = 0; h < 4; h++) {
        OvA[h] = *(const f32x4*)(Ovg + ((size_t)ia * 4 + h) * 64 + 4 * t);
        OvB[h] = NODE ? OvA[h] : *(const f32x4*)(Ovg + ((size_t)ib * 4 + h) * 64 + 4 * t);
    }
    float E0c = __expf(E0x[t]), E2c = __expf(E2x[t]);
    int rb = 0, st = 0;
    if (!NODE) { rb = rowbase[item]; st = estride[item]; }

    // softmax (no max-shift; scores |s| <~ 1.5): lane t owns combo (h=t>>2, m=t&3)
    {
        float den = E0c + Ea + E2c + Eb;
        float inv = 1.f / den;
        f32x4 wv = {E0c * inv, Ea * inv, E2c * inv, Eb * inv};
        *(f32x4*)&myscr[(g * 17 + t) * 4] = wv;      // wS
    }

    // Stage A: attention combine + LN1 per slot
    f32x4 g1v = *(const f32x4*)(ln1_g + 4 * t);
    f32x4 b1v = *(const f32x4*)(ln1_b + 4 * t);
    f32x4 x1a[4];
#pragma unroll
    for (int m = 0; m < 4; m++) {
        f32x4 x = *(const f32x4*)&clsS[m * 68 + 4 * t];
#pragma unroll
        for (int h = 0; h < 4; h++) {
            f32x4 wq = *(const f32x4*)&myscr[(g * 17 + h * 4 + m) * 4];
            f32x4 oc = *(const f32x4*)&OcS[(m * 4 + h) * 68 + 4 * t];
            f32x4 os = *(const f32x4*)&OsS[h * 68 + 4 * t];
            x += oc * wq.x + OvA[h] * wq.y + os * wq.z + OvB[h] * wq.w;
        }
        float s = (x.x + x.y) + (x.z + x.w);
        float s2 = dot4(x, x);
        s = hsum16d(s); s2 = hsum16d(s2);
        float mu = s * (1.f / 64.f);
        float var = s2 * (1.f / 64.f) - mu * mu;
        float r1 = rsqrtf(var + 1e-5f);
        x1a[m] = (x - mu) * (r1 * g1v) + b1v;
    }

    // Stage B1: FF1, hidden unit = lane t (no redundancy); scr reused as xS per slot
    float f1b = ff1_b[t];
    float hr[4];
#pragma unroll
    for (int m = 0; m < 4; m++) {
        *(f32x4*)&myscr[(g * 17 + t) * 4] = x1a[m];
        float hp = 0.f;
#pragma unroll
        for (int tj = 0; tj < 16; tj++) {
            f32x4 f1 = *(const f32x4*)&F1T[t * 68 + 4 * tj];
            f32x4 xv = *(const f32x4*)&myscr[(g * 17 + tj) * 4];
            hp += dot4(f1, xv);
        }
        hr[m] = fmaxf(hp + f1b, 0.f);
    }

    // Stage B2: FF2; scr reused as hS
    {
        f32x4 hv = {hr[0], hr[1], hr[2], hr[3]};
        *(f32x4*)&myscr[(g * 17 + t) * 4] = hv;
    }
    f32x4 f2bv = *(const f32x4*)(ff2_b + 4 * t);
    f32x4 y[4];
#pragma unroll
    for (int m = 0; m < 4; m++) y[m] = x1a[m] + f2bv;
#pragma unroll
    for (int tf = 0; tf < 16; tf++) {
        f32x4 hh = *(const f32x4*)&myscr[(g * 17 + tf) * 4];
        f32x4 f2 = *(const f32x4*)&F2T[tf * 68 + 4 * t];
        y[0] += f2 * hh.x;
        y[1] += f2 * hh.y;
        y[2] += f2 * hh.z;
        y[3] += f2 * hh.w;
    }

    // Stage C: LN2 + mem (+ cat for edges); scr reused as pS per slot
    f32x4 g2v = *(const f32x4*)(ln2_g + 4 * t);
    f32x4 b2v = *(const f32x4*)(ln2_b + 4 * t);
    f32x4 mem = {0.f, 0.f, 0.f, 0.f};
#pragma unroll
    for (int m = 0; m < 4; m++) {
        f32x4 ym = y[m];
        float s = (ym.x + ym.y) + (ym.z + ym.w);
        float s2 = dot4(ym, ym);
        s = hsum16d(s); s2 = hsum16d(s2);
        float mu2 = s * (1.f / 64.f);
        float var2 = s2 * (1.f / 64.f) - mu2 * mu2;
        float r2 = rsqrtf(var2 + 1e-5f);
        mem += (ym - mu2) * (r2 * g2v) + b2v;
        if (!NODE) {
            f32x4 p;
#pragma unroll
            for (int c = 0; c < 4; c++) {
                f32x4 mc = *(const f32x4*)&mcgS[c * 68 + 4 * t];
                p[c] = dot4(mc, ym);
            }
            *(f32x4*)&myscr[(g * 17 + t) * 4] = p;
            int cs = t & 3;
            float d = 0.f;
#pragma unroll
            for (int tj = 0; tj < 16; tj++) d += myscr[(g * 17 + tj) * 4 + cs];
            f32x4 Mc = ((const f32x4*)MC8)[0], Cc = ((const f32x4*)MC8)[1];
            float Mcc = cs == 0 ? Mc.x : (cs == 1 ? Mc.y : (cs == 2 ? Mc.z : Mc.w));
            float Ccc = cs == 0 ? Cc.x : (cs == 1 ? Cc.y : (cs == 2 ? Cc.z : Cc.w));
            float cval = r2 * (d - mu2 * Mcc) + Ccc;
            int row = rb + m * st;
            if (t < 4) out_cat[(size_t)row * 4 + t] = cval;
            if (t == 0) out_label[row] = (float)m;
        }
    }
    *(f32x4*)(mem_out + (size_t)item * 64 + 4 * t) = mem;
}

// ---------------- message bilinear via MFMA (unchanged) ----------------

template <bool NODE>
__global__ __launch_bounds__(256, 2) void msg_mfma(
    const float* __restrict__ feat, const int* __restrict__ src, const int* __restrict__ dstv,
    const float* __restrict__ memv, const unsigned short* __restrict__ Wstg,
    float* __restrict__ outv, int count) {
    constexpr int RS = 72;
    __shared__ __align__(16) unsigned short Wt[4 * 64 * RS];
    __shared__ float hT[4 * 256];
    int tid = threadIdx.x;
    int w = tid >> 6, lane = tid & 63;
    int m16 = lane & 15, q = lane >> 4;
    int blockbase = blockIdx.x * 256;
    int wavebase = w * 64;

    float memf[4][2][8];
#pragma unroll
    for (int Mt = 0; Mt < 4; Mt++) {
        int it = blockbase + wavebase + Mt * 16 + m16;
        if (it >= count) it = count - 1;
        const float* mrow = memv + (size_t)it * 64;
#pragma unroll
        for (int ks = 0; ks < 2; ks++) {
            float4 a = *(const float4*)(mrow + ks * 32 + q * 8);
            float4 b = *(const float4*)(mrow + ks * 32 + q * 8 + 4);
            memf[Mt][ks][0] = a.x; memf[Mt][ks][1] = a.y;
            memf[Mt][ks][2] = a.z; memf[Mt][ks][3] = a.w;
            memf[Mt][ks][4] = b.x; memf[Mt][ks][5] = b.y;
            memf[Mt][ks][6] = b.z; memf[Mt][ks][7] = b.w;
        }
    }
    f32x4 acc[4][4];
#pragma unroll
    for (int Mt = 0; Mt < 4; Mt++)
#pragma unroll
        for (int nt = 0; nt < 4; nt++) {
            f32x4 z = {0.f, 0.f, 0.f, 0.f};
            acc[Mt][nt] = z;
        }

    for (int ch = 0; ch < 16; ch++) {
        __syncthreads();
        const unsigned short* gsl = Wstg + (size_t)ch * 4 * 4096;
#pragma unroll
        for (int p = 0; p < 8; p++) {
            int flat = p * 2048 + tid * 8;
            int ic = flat >> 12, o = (flat >> 6) & 63, d = flat & 63;
            uint4 v = *(const uint4*)(gsl + flat);
            *(uint4*)&Wt[(ic * 64 + o) * RS + d] = v;
        }
        {
            int it = blockbase + tid;
            if (it >= count) it = count - 1;
            int hidx = NODE ? it : src[it];
            float4 hv = *(const float4*)(feat + (size_t)hidx * 64 + ch * 4);
            hT[0 * 256 + tid] = hv.x;
            hT[1 * 256 + tid] = hv.y;
            hT[2 * 256 + tid] = hv.z;
            hT[3 * 256 + tid] = hv.w;
        }
        __syncthreads();

#pragma unroll
        for (int il = 0; il < 4; il++) {
            float hM[4];
#pragma unroll
            for (int Mt = 0; Mt < 4; Mt++)
                hM[Mt] = hT[il * 256 + wavebase + Mt * 16 + m16];
            bf16x8 afr[4][2];
#pragma unroll
            for (int Mt = 0; Mt < 4; Mt++)
#pragma unroll
                for (int ks = 0; ks < 2; ks++) {
                    union { unsigned u[4]; bf16x8 v; } uu;
#pragma unroll
                    for (int jj = 0; jj < 4; jj++) {
                        float p0 = memf[Mt][ks][jj * 2 + 0] * hM[Mt];
                        float p1 = memf[Mt][ks][jj * 2 + 1] * hM[Mt];
                        uu.u[jj] = pack_bf2(p0, p1);
                    }
                    afr[Mt][ks] = uu.v;
                }
            const unsigned short* wrow = &Wt[(il * 64) * RS];
#pragma unroll
            for (int nt = 0; nt < 4; nt++) {
#pragma unroll
                for (int ks = 0; ks < 2; ks++) {
                    int o = nt * 16 + m16;
                    union { uint4 u; bf16x8 v; } bb;
                    bb.u = *(const uint4*)&wrow[o * RS + ks * 32 + q * 8];
#pragma unroll
                    for (int Mt = 0; Mt < 4; Mt++)
                        acc[Mt][nt] = __builtin_amdgcn_mfma_f32_16x16x32_bf16(
                            afr[Mt][ks], bb.v, acc[Mt][nt], 0, 0, 0);
                }
            }
        }
    }
#pragma unroll
    for (int Mt = 0; Mt < 4; Mt++) {
        int ib = blockbase + wavebase + Mt * 16 + q * 4;
        if (NODE) {
#pragma unroll
            for (int r = 0; r < 4; r++) {
                int it = ib + r;
                if (it < count) {
#pragma unroll
                    for (int nt = 0; nt < 4; nt++)
                        outv[(size_t)it * 64 + nt * 16 + m16] = acc[Mt][nt][r];
                }
            }
        } else {
            int4 dd = *(const int4*)(dstv + ib);
#pragma unroll
            for (int r = 0; r < 4; r++) {
                int it = ib + r;
                if (it < count) {
                    int dn = (&dd.x)[r];
#pragma unroll
                    for (int nt = 0; nt < 4; nt++)
                        atomicAdd(&outv[(size_t)dn * 64 + nt * 16 + m16], acc[Mt][nt][r]);
                }
            }
        }
    }
}

// ---------------- final node combine ----------------

__global__ __launch_bounds__(256) void final_kernel(
    const float* __restrict__ agg, const float* __restrict__ deg, const float* __restrict__ msgn,
    const float* __restrict__ lnw_g, const float* __restrict__ lnw_b,
    const float* __restrict__ h_bias, float* __restrict__ outp, int nN) {
    int tid = threadIdx.x, w = tid >> 6, l = tid & 63;
    int n = blockIdx.x * 4 + w;
    if (n >= nN) return;
    float a = agg[(size_t)n * 64 + l] / fmaxf(deg[n], 1.f);
    float mu = wsum64(a) * (1.f / 64.f);
    float d = a - mu;
    float var = wsum64(d * d) * (1.f / 64.f);
    float v = d * rsqrtf(var + 1e-5f) * lnw_g[l] + lnw_b[l] + h_bias[l] + msgn[(size_t)n * 64 + l];
    outp[(size_t)n * 64 + l] = v > 0.f ? v : 0.2f * v;
}

// ---------------- host ----------------

extern "C" void kernel_launch(void* const* d_in, const int* in_sizes, int n_in,
                              void* d_out, int out_size, void* d_ws, size_t ws_size,
                              hipStream_t stream) {
    const float* feat   = (const float*)d_in[0];
    const int*   src    = (const int*)d_in[1];
    const int*   dst    = (const int*)d_in[2];
    const int*   etype  = (const int*)d_in[3];
    const float* cls_w  = (const float*)d_in[4];
    const float* sep    = (const float*)d_in[5];
    const float* in_w   = (const float*)d_in[6];
    const float* in_b   = (const float*)d_in[7];
    const float* out_w  = (const float*)d_in[8];
    const float* out_b  = (const float*)d_in[9];
    const float* ln1_g  = (const float*)d_in[10];
    const float* ln1_b  = (const float*)d_in[11];
    const float* ln2_g  = (const float*)d_in[12];
    const float* ln2_b  = (const float*)d_in[13];
    const float* ff1_w  = (const float*)d_in[14];
    const float* ff1_b  = (const float*)d_in[15];
    const float* ff2_w  = (const float*)d_in[16];
    const float* ff2_b  = (const float*)d_in[17];
    const float* mc_w   = (const float*)d_in[18];
    const float* mc_b   = (const float*)d_in[19];
    const float* memw_w = (const float*)d_in[20];
    const float* h_bias = (const float*)d_in[21];
    const float* lnw_g  = (const float*)d_in[22];
    const float* lnw_b  = (const float*)d_in[23];

    char* ws = (char*)d_ws;
    size_t off = 0;
    auto nxt = [&](size_t bytes) -> void* {
        void* p = ws + off;
        off += (bytes + 255) & ~(size_t)255;
        return p;
    };
    unsigned short* Wstg = (unsigned short*)nxt(64 * 64 * 64 * sizeof(unsigned short));
    float* P       = (float*)nxt(1024 * sizeof(float));
    float* SWg     = (float*)nxt(1024 * sizeof(float));
    float* SB16    = (float*)nxt(16 * sizeof(float));
    float* OvcG    = (float*)nxt(1024 * sizeof(float));
    float* OvsG    = (float*)nxt(256 * sizeof(float));
    float* bOvG    = (float*)nxt(256 * sizeof(float));
    float* s0x     = (float*)nxt(16 * sizeof(float));
    float* s2x     = (float*)nxt(16 * sizeof(float));
    float* MC8     = (float*)nxt(8 * sizeof(float));
    float* WOVg    = (float*)nxt(16384 * sizeof(float));
    float* Eg      = (float*)nxt((size_t)NN * 16 * sizeof(float));
    float* Ovg     = (float*)nxt((size_t)NN * 256 * sizeof(float));
    int*   bc      = (int*)nxt(625 * 5 * sizeof(int));
    int*   boff    = (int*)nxt(625 * 5 * sizeof(int));
    int*   cs      = (int*)nxt(16 * sizeof(int));
    int*   rowbase = (int*)nxt((size_t)NE * sizeof(int));
    int*   estride = (int*)nxt((size_t)NE * sizeof(int));
    float* mem_e   = (float*)nxt((size_t)NE * 64 * sizeof(float));
    float* mem_n   = (float*)nxt((size_t)NN * 64 * sizeof(float));
    float* agg     = (float*)nxt((size_t)NN * 64 * sizeof(float));
    float* deg     = (float*)nxt((size_t)NN * sizeof(float));
    float* msg_n   = (float*)nxt((size_t)NN * 64 * sizeof(float));
    (void)ws_size; (void)in_sizes; (void)n_in; (void)out_size;

    float* out_node  = (float*)d_out;
    float* out_cat   = out_node + (size_t)NN * 64;
    float* out_label = out_cat + (size_t)4 * NE * 4;

    hipMemsetAsync(agg, 0, (size_t)NN * 64 * sizeof(float), stream);
    hipMemsetAsync(deg, 0, (size_t)NN * sizeof(float), stream);

    prep_w<<<1024, 256, 0, stream>>>(memw_w, Wstg);
    precomp_kernel<<<1, 64, 0, stream>>>(cls_w, sep, in_w, in_b, P);
    prep2_kernel<<<1, 256, 0, stream>>>(in_w, in_b, out_w, mc_w, mc_b, ln2_g, ln2_b, P,
                                        SWg, SB16, OvcG, OvsG, bOvG, s0x, s2x, MC8);
    prep_wov<<<64, 256, 0, stream>>>(in_w, out_w, WOVg);

    int nb = (NE + 255) / 256;  // 625
    hist_kernel<<<nb, 256, 0, stream>>>(etype, bc, NE);
    scan_kernel<<<1, 64, 0, stream>>>(bc, boff, cs, nb);
    rank_kernel<<<nb, 256, 0, stream>>>(etype, boff, cs, rowbase, estride, NE);
    deg_kernel<<<nb, 256, 0, stream>>>(dst, deg, NE);

    node_pre<<<NN / 4, 256, 0, stream>>>(feat, SWg, SB16, WOVg, bOvG, Eg, Ovg);

    enc4_kernel<false><<<NE / 16, 256, 0, stream>>>(
        src, dst, Eg, Ovg, OvcG, OvsG, s0x, s2x, MC8, cls_w, out_b,
        ln1_g, ln1_b, ln2_g, ln2_b, ff1_w, ff1_b, ff2_w, ff2_b, mc_w,
        rowbase, estride, mem_e, out_cat, out_label, NE);
    enc4_kernel<true><<<NN / 16, 256, 0, stream>>>(
        nullptr, nullptr, Eg, Ovg, OvcG, OvsG, s0x, s2x, MC8, cls_w, out_b,
        ln1_g, ln1_b, ln2_g, ln2_b, ff1_w, ff1_b, ff2_w, ff2_b, mc_w,
        nullptr, nullptr, mem_n, nullptr, nullptr, NN);

    msg_mfma<false><<<(NE + 255) / 256, 256, 0, stream>>>(feat, src, dst, mem_e, Wstg, agg, NE);
    msg_mfma<true><<<(NN + 255) / 256, 256, 0, stream>>>(feat, nullptr, nullptr, mem_n, Wstg, msg_n, NN);

    final_kernel<<<(NN + 3) / 4, 256, 0, stream>>>(agg, deg, msg_n, lnw_g, lnw_b, h_bias, out_node, NN);
}

// Round 6
// 964.020 us; speedup vs baseline: 1.0237x; 1.0103x over previous
//
#include <hip/hip_runtime.h>

#define DI __device__ __forceinline__

static constexpr int NN = 20000;   // nodes
static constexpr int NE = 160000;  // edges

typedef __attribute__((ext_vector_type(8))) short bf16x8;
typedef __attribute__((ext_vector_type(4))) float f32x4;

DI float rl(float v, int lane) {
    return __int_as_float(__builtin_amdgcn_readlane(__float_as_int(v), lane));
}
DI float xr(float v, int m) { return __shfl_xor(v, m, 64); }
DI float wsum64(float v) {
    v += xr(v, 1); v += xr(v, 2); v += xr(v, 4);
    v += xr(v, 8); v += xr(v, 16); v += xr(v, 32);
    return v;
}
DI float hsum16(float v) {
    v += xr(v, 1); v += xr(v, 2); v += xr(v, 4); v += xr(v, 8);
    return v;
}
// DPP 16-lane (row) butterfly reduction: pure VALU.
DI float hsum16d(float v) {
    v += __int_as_float(__builtin_amdgcn_mov_dpp(__float_as_int(v), 0xB1, 0xF, 0xF, true));   // xor1
    v += __int_as_float(__builtin_amdgcn_mov_dpp(__float_as_int(v), 0x4E, 0xF, 0xF, true));   // xor2
    v += __int_as_float(__builtin_amdgcn_mov_dpp(__float_as_int(v), 0x141, 0xF, 0xF, true));  // half mirror
    v += __int_as_float(__builtin_amdgcn_mov_dpp(__float_as_int(v), 0x140, 0xF, 0xF, true));  // row mirror
    return v;
}
DI float wsum64v(float v) {
    v = hsum16d(v);
    return (rl(v, 0) + rl(v, 16)) + (rl(v, 32) + rl(v, 48));
}
DI float dot4(f32x4 a, f32x4 b) { return a.x * b.x + a.y * b.y + a.z * b.z + a.w * b.w; }
DI unsigned short f2bf(float x) {
    unsigned u = __float_as_uint(x) + 0x8000u;
    return (unsigned short)(u >> 16);
}
DI unsigned pack_bf2(float x, float y) {
    unsigned ux = __float_as_uint(x) + 0x8000u;
    unsigned uy = __float_as_uint(y) + 0x8000u;
#if __has_builtin(__builtin_amdgcn_perm)
    return __builtin_amdgcn_perm(uy, ux, 0x07060302u);
#else
    return (ux >> 16) | (uy & 0xFFFF0000u);
#endif
}

// ---------------- prep: W -> bf16, layout [i][o][d] (for msg MFMA) ----------------
__global__ void prep_w(const float* __restrict__ mw, unsigned short* __restrict__ Wstg) {
    int idx = blockIdx.x * 256 + threadIdx.x;   // 262144 total
    int d = idx & 63, o = (idx >> 6) & 63, i = idx >> 12;
    Wstg[idx] = f2bf(mw[(o * 64 + i) * 64 + d]);
}

// per-slot edge-independent constants:
// P[0..255] q0[m][l] | P[256..511] vc[m][l] | P[512..575] vs[l]
// P[576..591] s0[m][h]*0.25 | P[592..607] s2[m][h]*0.25
__global__ void precomp_kernel(const float* __restrict__ cls_w, const float* __restrict__ sep,
                               const float* __restrict__ in_w, const float* __restrict__ in_b,
                               float* __restrict__ P) {
    int l = threadIdx.x;  // 64 threads
    float bq = in_b[l], bk = in_b[64 + l], bv = in_b[128 + l];
    float xs = sep[l];
    float ks = bk, vs = bv;
    for (int j = 0; j < 64; j++) {
        float xj = rl(xs, j);
        ks += in_w[(64 + l) * 64 + j] * xj;
        vs += in_w[(128 + l) * 64 + j] * xj;
    }
    P[512 + l] = vs;
    for (int m = 0; m < 4; m++) {
        float xc = cls_w[m * 64 + l];
        float q0 = bq, kc = bk, vc = bv;
        for (int j = 0; j < 64; j++) {
            float xj = rl(xc, j);
            q0 += in_w[l * 64 + j] * xj;
            kc += in_w[(64 + l) * 64 + j] * xj;
            vc += in_w[(128 + l) * 64 + j] * xj;
        }
        P[m * 64 + l] = q0;
        P[256 + m * 64 + l] = vc;
        float p0 = hsum16(q0 * kc);
        float p2 = hsum16(q0 * ks);
        if ((l & 15) == 0) {
            P[576 + m * 4 + (l >> 4)] = p0 * 0.25f;
            P[592 + m * 4 + (l >> 4)] = p2 * 0.25f;
        }
    }
}

// fused small matrices derived from P + weights (single block, 256 thr)
__global__ void prep2_kernel(const float* __restrict__ in_w, const float* __restrict__ in_b,
                             const float* __restrict__ out_w,
                             const float* __restrict__ mc_w, const float* __restrict__ mc_b,
                             const float* __restrict__ ln2_g, const float* __restrict__ ln2_b,
                             const float* __restrict__ P,
                             float* __restrict__ SWg, float* __restrict__ SB16,
                             float* __restrict__ OvcG, float* __restrict__ OvsG,
                             float* __restrict__ bOvG, float* __restrict__ s0x,
                             float* __restrict__ s2x, float* __restrict__ MC8) {
    int t = threadIdx.x;
    for (int u = t; u < 1024; u += 256) {       // SW
        int m = u >> 8, h = (u >> 6) & 3, j = u & 63;
        float acc = 0.f;
        for (int i = 0; i < 16; i++)
            acc += P[m * 64 + h * 16 + i] * in_w[(64 + h * 16 + i) * 64 + j];
        SWg[u] = 0.25f * acc;
    }
    for (int u = t; u < 1024; u += 256) {       // Ovc: OvcG[(m*64+l)*4+h]
        int h = u & 3, l = (u >> 2) & 63, m = u >> 8;
        float acc = 0.f;
        for (int i = 0; i < 16; i++)
            acc += out_w[l * 64 + h * 16 + i] * P[256 + m * 64 + h * 16 + i];
        OvcG[u] = acc;
    }
    if (t < 256) {                              // Ovs, bOv
        int h = t & 3, l = t >> 2;
        float a1 = 0.f, a2 = 0.f;
        for (int i = 0; i < 16; i++) {
            a1 += out_w[l * 64 + h * 16 + i] * P[512 + h * 16 + i];
            a2 += out_w[l * 64 + h * 16 + i] * in_b[128 + h * 16 + i];
        }
        OvsG[t] = a1;
        bOvG[t] = a2;
    }
    if (t < 16) {                               // SB16, s0x, s2x
        int m = t >> 2, h = t & 3;
        float acc = 0.f;
        for (int i = 0; i < 16; i++)
            acc += P[m * 64 + h * 16 + i] * in_b[64 + h * 16 + i];
        SB16[t] = 0.25f * acc;
        int h2 = t >> 2, m2 = t & 3;
        s0x[t] = P[576 + m2 * 4 + h2];           // [h*4+m]
        s2x[t] = P[592 + m2 * 4 + h2];
    }
    if (t < 8) {                                // Mc / Cc
        int c = t & 3;
        float acc = 0.f;
        if (t < 4) {
            for (int l = 0; l < 64; l++) acc += mc_w[c * 64 + l] * ln2_g[l];
        } else {
            for (int l = 0; l < 64; l++) acc += mc_w[c * 64 + l] * ln2_b[l];
            acc += mc_b[c];
        }
        MC8[t] = acc;
    }
}

// WOVg[(j*64+l)*4+h] = sum_i out_w[l][h16+i]*Wv[h16+i][j]
__global__ void prep_wov(const float* __restrict__ in_w, const float* __restrict__ out_w,
                         float* __restrict__ WOVg) {
    int u = blockIdx.x * 256 + threadIdx.x;     // 16384
    int h = u & 3, l = (u >> 2) & 63, j = u >> 8;
    float acc = 0.f;
    for (int i = 0; i < 16; i++)
        acc += out_w[l * 64 + h * 16 + i] * in_w[(128 + h * 16 + i) * 64 + j];
    WOVg[u] = acc;
}

// ---------------- per-node stage: Eg[n][h*4+m] = exp(S), Ov[n][h][l] ----------------
__global__ __launch_bounds__(256) void node_pre(
    const float* __restrict__ feat, const float* __restrict__ SWg,
    const float* __restrict__ SB16, const float* __restrict__ WOVg,
    const float* __restrict__ bOvG, float* __restrict__ Eout, float* __restrict__ Ovout) {
    __shared__ float SWs[1024];
    __shared__ f32x4 WOVs[4096];
    int tid = threadIdx.x;
    for (int p = tid; p < 1024; p += 256) SWs[p] = SWg[p];
    for (int p = tid; p < 4096; p += 256) WOVs[p] = ((const f32x4*)WOVg)[p];
    __syncthreads();
    int w = tid >> 6, l = tid & 63;
    int n = blockIdx.x * 4 + w;
    float f = feat[(size_t)n * 64 + l];
#pragma unroll
    for (int mh = 0; mh < 16; mh++) {           // mh = m*4+h
        float v = SWs[mh * 64 + l] * f;
        v = wsum64v(v);
        if (l == mh) Eout[(size_t)n * 16 + (mh & 3) * 4 + (mh >> 2)] = __expf(v + SB16[mh]);
    }
    f32x4 acc = ((const f32x4*)bOvG)[l];
#pragma unroll 8
    for (int j = 0; j < 64; j++) {
        float fj = rl(f, j);
        f32x4 wv = WOVs[j * 64 + l];
        acc += wv * fj;
    }
#pragma unroll
    for (int h = 0; h < 4; h++)
        Ovout[((size_t)n * 4 + h) * 64 + l] = acc[h];
}

// ---------------- edge-order bookkeeping ----------------

__global__ void hist_kernel(const int* __restrict__ et, int* __restrict__ bc, int nE) {
    __shared__ int c[5];
    int t = threadIdx.x, b = blockIdx.x;
    if (t < 5) c[t] = 0;
    __syncthreads();
    int e = b * 256 + t;
    if (e < nE) atomicAdd(&c[et[e]], 1);
    __syncthreads();
    if (t < 5) bc[b * 5 + t] = c[t];
}

__global__ void scan_kernel(const int* __restrict__ bc, int* __restrict__ boff,
                            int* __restrict__ cs, int nb) {
    int t = threadIdx.x;
    if (t < 5) {
        int tot = 0;
        for (int b = 0; b < nb; b++) { boff[b * 5 + t] = tot; tot += bc[b * 5 + t]; }
        cs[t] = tot;
    }
    __syncthreads();
    if (t == 0) {
        int s = 0;
        for (int e = 0; e < 5; e++) { cs[5 + e] = s; s += cs[e]; }
    }
}

__global__ void rank_kernel(const int* __restrict__ et, const int* __restrict__ boff,
                            const int* __restrict__ cs, int* __restrict__ rowbase,
                            int* __restrict__ estride, int nE) {
    __shared__ int wc[4][5];
    int tid = threadIdx.x, b = blockIdx.x;
    int w = tid >> 6, lane = tid & 63;
    int e = b * 256 + tid;
    bool valid = e < nE;
    int my = valid ? et[e] : 0;
    unsigned long long bal[5];
#pragma unroll
    for (int ty = 0; ty < 5; ty++) bal[ty] = __ballot(valid && my == ty);
    if (lane == 0) {
#pragma unroll
        for (int ty = 0; ty < 5; ty++) wc[w][ty] = __popcll(bal[ty]);
    }
    __syncthreads();
    if (valid) {
        unsigned long long lt = ((unsigned long long)1 << lane) - 1;
        int intra = __popcll(bal[my] & lt);
        int pre = 0;
        for (int w2 = 0; w2 < w; w2++) pre += wc[w2][my];
        rowbase[e] = 4 * cs[5 + my] + boff[b * 5 + my] + pre + intra;
        estride[e] = cs[my];
    }
}

__global__ void deg_kernel(const int* __restrict__ dst, float* __restrict__ deg, int nE) {
    int e = blockIdx.x * 256 + threadIdx.x;
    if (e < nE) atomicAdd(&deg[dst[e]], 1.0f);
}

// ---------------- encoder v5: 4 items/wave, 16 lanes/item, 4 dims/lane ----------------
// Stage A is h-outer so only ONE Ov fragment pair is live at a time: peak live state
// ~55 VGPRs (R4/R5's m-outer held OvA[4]+OvB[4]+x1a[4]+y[4] = 64 VGPRs of arrays live
// simultaneously and spilled ~1 GB to scratch at the allocator's 64-reg choice).
// Requires count % 16 == 0.

template <bool NODE>
__global__ __launch_bounds__(256, 4) void enc5_kernel(
    const int* __restrict__ src, const int* __restrict__ dst,
    const float* __restrict__ Eg, const float* __restrict__ Ovg,
    const float* __restrict__ OvcG, const float* __restrict__ OvsG,
    const float* __restrict__ E0x, const float* __restrict__ E2x,
    const float* __restrict__ MC8,
    const float* __restrict__ cls_w, const float* __restrict__ out_b,
    const float* __restrict__ ln1_g, const float* __restrict__ ln1_b,
    const float* __restrict__ ln2_g, const float* __restrict__ ln2_b,
    const float* __restrict__ ff1_w, const float* __restrict__ ff1_b,
    const float* __restrict__ ff2_w, const float* __restrict__ ff2_b,
    const float* __restrict__ mc_w,
    const int* __restrict__ rowbase, const int* __restrict__ estride,
    float* __restrict__ mem_out, float* __restrict__ out_cat, float* __restrict__ out_label,
    int count) {
    // row stride 68 floats = 272B (16B-aligned, bank-offset 4)
    __shared__ float OcS[16 * 68];   // [(m*4+h)][l]
    __shared__ float OsS[4 * 68];    // [h][l]
    __shared__ float clsS[4 * 68];   // [m][l] = cls + out_b
    __shared__ float F1T[16 * 68];   // [f][j]
    __shared__ float F2T[16 * 68];   // [f][l]
    __shared__ float mcgS[4 * 68];   // [c][l] = mc_w[c][l]*g2[l]
    __shared__ float scr[4 * 272];   // per-wave scratch: 68 x f32x4 units (wS->xS->hS->pS)

    int tid = threadIdx.x;
    for (int p = tid; p < 1024; p += 256) {
        int m = p >> 8, h = (p >> 6) & 3, l = p & 63;
        OcS[(m * 4 + h) * 68 + l] = OvcG[(m * 64 + l) * 4 + h];
        int f = p >> 6, j = p & 63;
        F1T[f * 68 + j] = ff1_w[p];                  // ff1_w[f*64+j]
        F2T[f * 68 + j] = ff2_w[j * 16 + f];         // [f][l]
    }
    {
        int h = tid & 3, l = tid >> 2;
        OsS[h * 68 + l] = OvsG[l * 4 + h];
        int m = tid >> 6, l2 = tid & 63;
        clsS[m * 68 + l2] = cls_w[m * 64 + l2] + out_b[l2];
        int c = tid >> 6;
        mcgS[c * 68 + l2] = mc_w[c * 64 + l2] * ln2_g[l2];
    }
    __syncthreads();

    int w = tid >> 6, lane = tid & 63;
    int g = lane >> 4, t = lane & 15;
    float* myscr = scr + w * 272;                    // 68 f32x4 units
    int item = blockIdx.x * 16 + w * 4 + g;

    int ia = NODE ? item : src[item];
    int ib = NODE ? item : dst[item];

    // softmax (no max-shift; scores |s| <~ 1.5): lane t owns combo (h=t>>2, m=t&3)
    {
        float Ea = Eg[(size_t)ia * 16 + t];
        float Eb = NODE ? Ea : Eg[(size_t)ib * 16 + t];
        float E0c = __expf(E0x[t]), E2c = __expf(E2x[t]);
        float den = E0c + Ea + E2c + Eb;
        float inv = 1.f / den;
        f32x4 wv = {E0c * inv, Ea * inv, E2c * inv, Eb * inv};
        *(f32x4*)&myscr[(g * 17 + t) * 4] = wv;      // wS
    }

    // Stage A: attention combine, h-outer (one Ov pair live at a time)
    f32x4 x[4];
#pragma unroll
    for (int m = 0; m < 4; m++) x[m] = *(const f32x4*)&clsS[m * 68 + 4 * t];
#pragma unroll
    for (int h = 0; h < 4; h++) {
        f32x4 OvAh = *(const f32x4*)(Ovg + ((size_t)ia * 4 + h) * 64 + 4 * t);
        f32x4 OvBh = NODE ? OvAh : *(const f32x4*)(Ovg + ((size_t)ib * 4 + h) * 64 + 4 * t);
        f32x4 osh = *(const f32x4*)&OsS[h * 68 + 4 * t];
#pragma unroll
        for (int m = 0; m < 4; m++) {
            f32x4 wq = *(const f32x4*)&myscr[(g * 17 + h * 4 + m) * 4];
            f32x4 oc = *(const f32x4*)&OcS[(m * 4 + h) * 68 + 4 * t];
            x[m] += oc * wq.x + OvAh * wq.y + osh * wq.z + OvBh * wq.w;
        }
    }
    // LN1 in place
    {
        f32x4 g1v = *(const f32x4*)(ln1_g + 4 * t);
        f32x4 b1v = *(const f32x4*)(ln1_b + 4 * t);
#pragma unroll
        for (int m = 0; m < 4; m++) {
            f32x4 xm = x[m];
            float s = (xm.x + xm.y) + (xm.z + xm.w);
            float s2 = dot4(xm, xm);
            s = hsum16d(s); s2 = hsum16d(s2);
            float mu = s * (1.f / 64.f);
            float var = s2 * (1.f / 64.f) - mu * mu;
            float r1 = rsqrtf(var + 1e-5f);
            x[m] = (xm - mu) * (r1 * g1v) + b1v;
        }
    }

    // Stage B1: FF1, hidden unit = lane t (no redundancy); scr reused as xS per slot
    float f1b = ff1_b[t];
    float hr[4];
#pragma unroll
    for (int m = 0; m < 4; m++) {
        *(f32x4*)&myscr[(g * 17 + t) * 4] = x[m];
        float hp = 0.f;
#pragma unroll
        for (int tj = 0; tj < 16; tj++) {
            f32x4 f1 = *(const f32x4*)&F1T[t * 68 + 4 * tj];
            f32x4 xv = *(const f32x4*)&myscr[(g * 17 + tj) * 4];
            hp += dot4(f1, xv);
        }
        hr[m] = fmaxf(hp + f1b, 0.f);
    }

    // Stage B2: FF2; scr reused as hS; y accumulates over x (residual)
    {
        f32x4 hv = {hr[0], hr[1], hr[2], hr[3]};
        *(f32x4*)&myscr[(g * 17 + t) * 4] = hv;
    }
    {
        f32x4 f2bv = *(const f32x4*)(ff2_b + 4 * t);
#pragma unroll
        for (int m = 0; m < 4; m++) x[m] += f2bv;
    }
#pragma unroll
    for (int tf = 0; tf < 16; tf++) {
        f32x4 hh = *(const f32x4*)&myscr[(g * 17 + tf) * 4];
        f32x4 f2 = *(const f32x4*)&F2T[tf * 68 + 4 * t];
        x[0] += f2 * hh.x;
        x[1] += f2 * hh.y;
        x[2] += f2 * hh.z;
        x[3] += f2 * hh.w;
    }

    // Stage C: LN2 + mem (+ cat for edges); scr reused as pS per slot
    int rb = 0, st = 0;
    if (!NODE) { rb = rowbase[item]; st = estride[item]; }
    f32x4 g2v = *(const f32x4*)(ln2_g + 4 * t);
    f32x4 b2v = *(const f32x4*)(ln2_b + 4 * t);
    f32x4 mem = {0.f, 0.f, 0.f, 0.f};
#pragma unroll
    for (int m = 0; m < 4; m++) {
        f32x4 ym = x[m];
        float s = (ym.x + ym.y) + (ym.z + ym.w);
        float s2 = dot4(ym, ym);
        s = hsum16d(s); s2 = hsum16d(s2);
        float mu2 = s * (1.f / 64.f);
        float var2 = s2 * (1.f / 64.f) - mu2 * mu2;
        float r2 = rsqrtf(var2 + 1e-5f);
        mem += (ym - mu2) * (r2 * g2v) + b2v;
        if (!NODE) {
            f32x4 p;
#pragma unroll
            for (int c = 0; c < 4; c++) {
                f32x4 mc = *(const f32x4*)&mcgS[c * 68 + 4 * t];
                p[c] = dot4(mc, ym);
            }
            *(f32x4*)&myscr[(g * 17 + t) * 4] = p;
            int cs = t & 3;
            float d = 0.f;
#pragma unroll
            for (int tj = 0; tj < 16; tj++) d += myscr[(g * 17 + tj) * 4 + cs];
            f32x4 Mc = ((const f32x4*)MC8)[0], Cc = ((const f32x4*)MC8)[1];
            float Mcc = cs == 0 ? Mc.x : (cs == 1 ? Mc.y : (cs == 2 ? Mc.z : Mc.w));
            float Ccc = cs == 0 ? Cc.x : (cs == 1 ? Cc.y : (cs == 2 ? Cc.z : Cc.w));
            float cval = r2 * (d - mu2 * Mcc) + Ccc;
            int row = rb + m * st;
            if (t < 4) out_cat[(size_t)row * 4 + t] = cval;
            if (t == 0) out_label[row] = (float)m;
        }
    }
    *(f32x4*)(mem_out + (size_t)item * 64 + 4 * t) = mem;
}

// ---------------- message bilinear via MFMA (unchanged) ----------------

template <bool NODE>
__global__ __launch_bounds__(256, 2) void msg_mfma(
    const float* __restrict__ feat, const int* __restrict__ src, const int* __restrict__ dstv,
    const float* __restrict__ memv, const unsigned short* __restrict__ Wstg,
    float* __restrict__ outv, int count) {
    constexpr int RS = 72;
    __shared__ __align__(16) unsigned short Wt[4 * 64 * RS];
    __shared__ float hT[4 * 256];
    int tid = threadIdx.x;
    int w = tid >> 6, lane = tid & 63;
    int m16 = lane & 15, q = lane >> 4;
    int blockbase = blockIdx.x * 256;
    int wavebase = w * 64;

    float memf[4][2][8];
#pragma unroll
    for (int Mt = 0; Mt < 4; Mt++) {
        int it = blockbase + wavebase + Mt * 16 + m16;
        if (it >= count) it = count - 1;
        const float* mrow = memv + (size_t)it * 64;
#pragma unroll
        for (int ks = 0; ks < 2; ks++) {
            float4 a = *(const float4*)(mrow + ks * 32 + q * 8);
            float4 b = *(const float4*)(mrow + ks * 32 + q * 8 + 4);
            memf[Mt][ks][0] = a.x; memf[Mt][ks][1] = a.y;
            memf[Mt][ks][2] = a.z; memf[Mt][ks][3] = a.w;
            memf[Mt][ks][4] = b.x; memf[Mt][ks][5] = b.y;
            memf[Mt][ks][6] = b.z; memf[Mt][ks][7] = b.w;
        }
    }
    f32x4 acc[4][4];
#pragma unroll
    for (int Mt = 0; Mt < 4; Mt++)
#pragma unroll
        for (int nt = 0; nt < 4; nt++) {
            f32x4 z = {0.f, 0.f, 0.f, 0.f};
            acc[Mt][nt] = z;
        }

    for (int ch = 0; ch < 16; ch++) {
        __syncthreads();
        const unsigned short* gsl = Wstg + (size_t)ch * 4 * 4096;
#pragma unroll
        for (int p = 0; p < 8; p++) {
            int flat = p * 2048 + tid * 8;
            int ic = flat >> 12, o = (flat >> 6) & 63, d = flat & 63;
            uint4 v = *(const uint4*)(gsl + flat);
            *(uint4*)&Wt[(ic * 64 + o) * RS + d] = v;
        }
        {
            int it = blockbase + tid;
            if (it >= count) it = count - 1;
            int hidx = NODE ? it : src[it];
            float4 hv = *(const float4*)(feat + (size_t)hidx * 64 + ch * 4);
            hT[0 * 256 + tid] = hv.x;
            hT[1 * 256 + tid] = hv.y;
            hT[2 * 256 + tid] = hv.z;
            hT[3 * 256 + tid] = hv.w;
        }
        __syncthreads();

#pragma unroll
        for (int il = 0; il < 4; il++) {
            float hM[4];
#pragma unroll
            for (int Mt = 0; Mt < 4; Mt++)
                hM[Mt] = hT[il * 256 + wavebase + Mt * 16 + m16];
            bf16x8 afr[4][2];
#pragma unroll
            for (int Mt = 0; Mt < 4; Mt++)
#pragma unroll
                for (int ks = 0; ks < 2; ks++) {
                    union { unsigned u[4]; bf16x8 v; } uu;
#pragma unroll
                    for (int jj = 0; jj < 4; jj++) {
                        float p0 = memf[Mt][ks][jj * 2 + 0] * hM[Mt];
                        float p1 = memf[Mt][ks][jj * 2 + 1] * hM[Mt];
                        uu.u[jj] = pack_bf2(p0, p1);
                    }
                    afr[Mt][ks] = uu.v;
                }
            const unsigned short* wrow = &Wt[(il * 64) * RS];
#pragma unroll
            for (int nt = 0; nt < 4; nt++) {
#pragma unroll
                for (int ks = 0; ks < 2; ks++) {
                    int o = nt * 16 + m16;
                    union { uint4 u; bf16x8 v; } bb;
                    bb.u = *(const uint4*)&wrow[o * RS + ks * 32 + q * 8];
#pragma unroll
                    for (int Mt = 0; Mt < 4; Mt++)
                        acc[Mt][nt] = __builtin_amdgcn_mfma_f32_16x16x32_bf16(
                            afr[Mt][ks], bb.v, acc[Mt][nt], 0, 0, 0);
                }
            }
        }
    }
#pragma unroll
    for (int Mt = 0; Mt < 4; Mt++) {
        int ib = blockbase + wavebase + Mt * 16 + q * 4;
        if (NODE) {
#pragma unroll
            for (int r = 0; r < 4; r++) {
                int it = ib + r;
                if (it < count) {
#pragma unroll
                    for (int nt = 0; nt < 4; nt++)
                        outv[(size_t)it * 64 + nt * 16 + m16] = acc[Mt][nt][r];
                }
            }
        } else {
            int4 dd = *(const int4*)(dstv + ib);
#pragma unroll
            for (int r = 0; r < 4; r++) {
                int it = ib + r;
                if (it < count) {
                    int dn = (&dd.x)[r];
#pragma unroll
                    for (int nt = 0; nt < 4; nt++)
                        atomicAdd(&outv[(size_t)dn * 64 + nt * 16 + m16], acc[Mt][nt][r]);
                }
            }
        }
    }
}

// ---------------- final node combine ----------------

__global__ __launch_bounds__(256) void final_kernel(
    const float* __restrict__ agg, const float* __restrict__ deg, const float* __restrict__ msgn,
    const float* __restrict__ lnw_g, const float* __restrict__ lnw_b,
    const float* __restrict__ h_bias, float* __restrict__ outp, int nN) {
    int tid = threadIdx.x, w = tid >> 6, l = tid & 63;
    int n = blockIdx.x * 4 + w;
    if (n >= nN) return;
    float a = agg[(size_t)n * 64 + l] / fmaxf(deg[n], 1.f);
    float mu = wsum64(a) * (1.f / 64.f);
    float d = a - mu;
    float var = wsum64(d * d) * (1.f / 64.f);
    float v = d * rsqrtf(var + 1e-5f) * lnw_g[l] + lnw_b[l] + h_bias[l] + msgn[(size_t)n * 64 + l];
    outp[(size_t)n * 64 + l] = v > 0.f ? v : 0.2f * v;
}

// ---------------- host ----------------

extern "C" void kernel_launch(void* const* d_in, const int* in_sizes, int n_in,
                              void* d_out, int out_size, void* d_ws, size_t ws_size,
                              hipStream_t stream) {
    const float* feat   = (const float*)d_in[0];
    const int*   src    = (const int*)d_in[1];
    const int*   dst    = (const int*)d_in[2];
    const int*   etype  = (const int*)d_in[3];
    const float* cls_w  = (const float*)d_in[4];
    const float* sep    = (const float*)d_in[5];
    const float* in_w   = (const float*)d_in[6];
    const float* in_b   = (const float*)d_in[7];
    const float* out_w  = (const float*)d_in[8];
    const float* out_b  = (const float*)d_in[9];
    const float* ln1_g  = (const float*)d_in[10];
    const float* ln1_b  = (const float*)d_in[11];
    const float* ln2_g  = (const float*)d_in[12];
    const float* ln2_b  = (const float*)d_in[13];
    const float* ff1_w  = (const float*)d_in[14];
    const float* ff1_b  = (const float*)d_in[15];
    const float* ff2_w  = (const float*)d_in[16];
    const float* ff2_b  = (const float*)d_in[17];
    const float* mc_w   = (const float*)d_in[18];
    const float* mc_b   = (const float*)d_in[19];
    const float* memw_w = (const float*)d_in[20];
    const float* h_bias = (const float*)d_in[21];
    const float* lnw_g  = (const float*)d_in[22];
    const float* lnw_b  = (const float*)d_in[23];

    char* ws = (char*)d_ws;
    size_t off = 0;
    auto nxt = [&](size_t bytes) -> void* {
        void* p = ws + off;
        off += (bytes + 255) & ~(size_t)255;
        return p;
    };
    unsigned short* Wstg = (unsigned short*)nxt(64 * 64 * 64 * sizeof(unsigned short));
    float* P       = (float*)nxt(1024 * sizeof(float));
    float* SWg     = (float*)nxt(1024 * sizeof(float));
    float* SB16    = (float*)nxt(16 * sizeof(float));
    float* OvcG    = (float*)nxt(1024 * sizeof(float));
    float* OvsG    = (float*)nxt(256 * sizeof(float));
    float* bOvG    = (float*)nxt(256 * sizeof(float));
    float* s0x     = (float*)nxt(16 * sizeof(float));
    float* s2x     = (float*)nxt(16 * sizeof(float));
    float* MC8     = (float*)nxt(8 * sizeof(float));
    float* WOVg    = (float*)nxt(16384 * sizeof(float));
    float* Eg      = (float*)nxt((size_t)NN * 16 * sizeof(float));
    float* Ovg     = (float*)nxt((size_t)NN * 256 * sizeof(float));
    int*   bc      = (int*)nxt(625 * 5 * sizeof(int));
    int*   boff    = (int*)nxt(625 * 5 * sizeof(int));
    int*   cs      = (int*)nxt(16 * sizeof(int));
    int*   rowbase = (int*)nxt((size_t)NE * sizeof(int));
    int*   estride = (int*)nxt((size_t)NE * sizeof(int));
    float* mem_e   = (float*)nxt((size_t)NE * 64 * sizeof(float));
    float* mem_n   = (float*)nxt((size_t)NN * 64 * sizeof(float));
    float* agg     = (float*)nxt((size_t)NN * 64 * sizeof(float));
    float* deg     = (float*)nxt((size_t)NN * sizeof(float));
    float* msg_n   = (float*)nxt((size_t)NN * 64 * sizeof(float));
    (void)ws_size; (void)in_sizes; (void)n_in; (void)out_size;

    float* out_node  = (float*)d_out;
    float* out_cat   = out_node + (size_t)NN * 64;
    float* out_label = out_cat + (size_t)4 * NE * 4;

    hipMemsetAsync(agg, 0, (size_t)NN * 64 * sizeof(float), stream);
    hipMemsetAsync(deg, 0, (size_t)NN * sizeof(float), stream);

    prep_w<<<1024, 256, 0, stream>>>(memw_w, Wstg);
    precomp_kernel<<<1, 64, 0, stream>>>(cls_w, sep, in_w, in_b, P);
    prep2_kernel<<<1, 256, 0, stream>>>(in_w, in_b, out_w, mc_w, mc_b, ln2_g, ln2_b, P,
                                        SWg, SB16, OvcG, OvsG, bOvG, s0x, s2x, MC8);
    prep_wov<<<64, 256, 0, stream>>>(in_w, out_w, WOVg);

    int nb = (NE + 255) / 256;  // 625
    hist_kernel<<<nb, 256, 0, stream>>>(etype, bc, NE);
    scan_kernel<<<1, 64, 0, stream>>>(bc, boff, cs, nb);
    rank_kernel<<<nb, 256, 0, stream>>>(etype, boff, cs, rowbase, estride, NE);
    deg_kernel<<<nb, 256, 0, stream>>>(dst, deg, NE);

    node_pre<<<NN / 4, 256, 0, stream>>>(feat, SWg, SB16, WOVg, bOvG, Eg, Ovg);

    enc5_kernel<false><<<NE / 16, 256, 0, stream>>>(
        src, dst, Eg, Ovg, OvcG, OvsG, s0x, s2x, MC8, cls_w, out_b,
        ln1_g, ln1_b, ln2_g, ln2_b, ff1_w, ff1_b, ff2_w, ff2_b, mc_w,
        rowbase, estride, mem_e, out_cat, out_label, NE);
    enc5_kernel<true><<<NN / 16, 256, 0, stream>>>(
        nullptr, nullptr, Eg, Ovg, OvcG, OvsG, s0x, s2x, MC8, cls_w, out_b,
        ln1_g, ln1_b, ln2_g, ln2_b, ff1_w, ff1_b, ff2_w, ff2_b, mc_w,
        nullptr, nullptr, mem_n, nullptr, nullptr, NN);

    msg_mfma<false><<<(NE + 255) / 256, 256, 0, stream>>>(feat, src, dst, mem_e, Wstg, agg, NE);
    msg_mfma<true><<<(NN + 255) / 256, 256, 0, stream>>>(feat, nullptr, nullptr, mem_n, Wstg, msg_n, NN);

    final_kernel<<<(NN + 3) / 4, 256, 0, stream>>>(agg, deg, msg_n, lnw_g, lnw_b, h_bias, out_node, NN);
}